// Round 6
// baseline (247.106 us; speedup 1.0000x reference)
//
#include <hip/hip_runtime.h>
#include <hip/hip_bf16.h>

#define N_NODES 50000
#define N_EDGES 800000
#define D_IN    512
#define D_OUT   256
#define NBLK_SCAN ((N_NODES + 1023) / 1024)   // 49

typedef short s8v  __attribute__((ext_vector_type(8)));
typedef float f32x4 __attribute__((ext_vector_type(4)));

__device__ __forceinline__ unsigned short bf16b(float f) {
    __hip_bfloat16 h = __float2bfloat16(f);
    return *reinterpret_cast<unsigned short*>(&h);
}

__device__ __forceinline__ int wave_incl_scan(int v, int lane) {
    #pragma unroll
    for (int d = 1; d < 64; d <<= 1) {
        int u = __shfl_up(v, d, 64);
        if (lane >= d) v += u;
    }
    return v;
}

// ============ CSR build ============

__global__ void k_count(const int* __restrict__ col, int* __restrict__ cnt) {
    int i = blockIdx.x * 256 + threadIdx.x;
    if (i < N_EDGES) atomicAdd(&cnt[col[i]], 1);
}

__launch_bounds__(256)
__global__ void k_scan1(const int* __restrict__ cnt, int* __restrict__ bsum) {
    const int t = threadIdx.x, b = blockIdx.x;
    const int idx = b * 1024 + t * 4;
    int4 v = make_int4(0, 0, 0, 0);
    if (idx < N_NODES) v = *(const int4*)&cnt[idx];
    int s = v.x + v.y + v.z + v.w;
    #pragma unroll
    for (int d = 1; d < 64; d <<= 1) s += __shfl_xor(s, d, 64);
    __shared__ int ws[4];
    if ((t & 63) == 0) ws[t >> 6] = s;
    __syncthreads();
    if (t == 0) bsum[b] = ws[0] + ws[1] + ws[2] + ws[3];
}

__global__ void k_scan2(const int* __restrict__ bsum, int* __restrict__ boff) {
    const int t = threadIdx.x;   // 64
    int v = (t < NBLK_SCAN) ? bsum[t] : 0;
    int inc = wave_incl_scan(v, t);
    if (t < NBLK_SCAN) boff[t] = inc - v;
}

__launch_bounds__(256)
__global__ void k_scan3(const int* __restrict__ cnt, const int* __restrict__ boff,
                        int* __restrict__ row_ptr, float* __restrict__ dinv,
                        int* __restrict__ cursor) {
    const int t = threadIdx.x, b = blockIdx.x;
    const int lane = t & 63, wv = t >> 6;
    const int idx = b * 1024 + t * 4;
    int4 v = make_int4(0, 0, 0, 0);
    if (idx < N_NODES) v = *(const int4*)&cnt[idx];
    int s = v.x + v.y + v.z + v.w;
    int isc = wave_incl_scan(s, lane);
    __shared__ int wsum[4];
    if (lane == 63) wsum[wv] = isc;
    __syncthreads();
    int off = boff[b];
    #pragma unroll
    for (int i = 0; i < 4; ++i)
        if (i < wv) off += wsum[i];
    int p0 = off + isc - s;
    int p1 = p0 + v.x;
    int p2 = p1 + v.y;
    int p3 = p2 + v.z;
    if (idx < N_NODES) {
        row_ptr[idx + 0] = p0; cursor[idx + 0] = p0; dinv[idx + 0] = rsqrtf(1.f + (float)v.x);
        row_ptr[idx + 1] = p1; cursor[idx + 1] = p1; dinv[idx + 1] = rsqrtf(1.f + (float)v.y);
        row_ptr[idx + 2] = p2; cursor[idx + 2] = p2; dinv[idx + 2] = rsqrtf(1.f + (float)v.z);
        row_ptr[idx + 3] = p3; cursor[idx + 3] = p3; dinv[idx + 3] = rsqrtf(1.f + (float)v.w);
    }
    if (b == 0 && t == 0) row_ptr[N_NODES] = N_EDGES;
}

__global__ void k_fill(const int* __restrict__ row, const int* __restrict__ col,
                       int* __restrict__ cursor, int* __restrict__ csr_src) {
    int i = blockIdx.x * 256 + threadIdx.x;
    if (i < N_EDGES) {
        int pos = atomicAdd(&cursor[col[i]], 1);
        csr_src[pos] = row[i];
    }
}

// ============ W transpose + bf16 convert ============
__global__ void k_wt(const float* __restrict__ W, unsigned short* __restrict__ Wt) {
    int k = blockIdx.x;      // 512
    int n = threadIdx.x;     // 256
    Wt[(size_t)n * D_IN + k] = bf16b(W[(size_t)k * D_OUT + n]);
}

// ============ MFMA GEMM with reg-staged prefetch ============
// __launch_bounds__(256,3): grid caps occupancy at 3 blocks/CU anyway; this
// raises the VGPR cap to ~170 so the prefetch registers don't spill (round-5
// lesson: VGPR=96 cap spilled 48 prefetch regs -> WRITE_SIZE 25->88 MB).
__launch_bounds__(256, 3)
__global__ void k_gemm(const float* __restrict__ A,            // [N_NODES, 512] fp32
                       const unsigned short* __restrict__ Wt,  // [256, 512] bf16
                       const float* __restrict__ dinv,
                       unsigned short* __restrict__ yb)        // [N_NODES, 256] bf16
{
    __shared__ __align__(16) unsigned short As[128 * 64];   // [m][k], swizzled
    __shared__ __align__(16) unsigned short Bs[128 * 64];   // [n][k], swizzled

    const int t  = threadIdx.x;
    const int nt = blockIdx.x & 1;
    const int mt = blockIdx.x >> 1;
    const int m0 = mt * 128;
    const int n0 = nt * 128;

    const int w  = t >> 6;
    const int l  = t & 63;
    const int wm = (w >> 1) * 64;
    const int wn = (w & 1) * 64;
    const int lr = l & 15;
    const int lk = l >> 4;

    const int sr   = t >> 3;
    const int skg  = t & 7;
    const int swz  = (sr & 7) << 4;
    const int aswz = (lr & 7) << 4;

    f32x4 acc[4][4] = {};

    const float* aptr0;
    const float* aptr1;
    const float* aptr2;
    const float* aptr3;
    {
        int r0 = m0 + 0 * 32 + sr; if (r0 >= N_NODES) r0 = 0;
        int r1 = m0 + 1 * 32 + sr; if (r1 >= N_NODES) r1 = 0;
        int r2 = m0 + 2 * 32 + sr; if (r2 >= N_NODES) r2 = 0;
        int r3 = m0 + 3 * 32 + sr; if (r3 >= N_NODES) r3 = 0;
        aptr0 = &A[(size_t)r0 * D_IN + skg * 8];
        aptr1 = &A[(size_t)r1 * D_IN + skg * 8];
        aptr2 = &A[(size_t)r2 * D_IN + skg * 8];
        aptr3 = &A[(size_t)r3 * D_IN + skg * 8];
    }
    const unsigned short* wptr = &Wt[(size_t)(n0 + sr) * D_IN + skg * 8];

    float4 a0[4], a1[4];
    uint4  wq[4];

    #define LOADK(koff)                                                    \
        do {                                                               \
            a0[0] = *(const float4*)(aptr0 + (koff));                      \
            a1[0] = *(const float4*)(aptr0 + (koff) + 4);                  \
            a0[1] = *(const float4*)(aptr1 + (koff));                      \
            a1[1] = *(const float4*)(aptr1 + (koff) + 4);                  \
            a0[2] = *(const float4*)(aptr2 + (koff));                      \
            a1[2] = *(const float4*)(aptr2 + (koff) + 4);                  \
            a0[3] = *(const float4*)(aptr3 + (koff));                      \
            a1[3] = *(const float4*)(aptr3 + (koff) + 4);                  \
            wq[0] = *(const uint4*)(wptr + (size_t)0 * 32 * D_IN + (koff));\
            wq[1] = *(const uint4*)(wptr + (size_t)1 * 32 * D_IN + (koff));\
            wq[2] = *(const uint4*)(wptr + (size_t)2 * 32 * D_IN + (koff));\
            wq[3] = *(const uint4*)(wptr + (size_t)3 * 32 * D_IN + (koff));\
        } while (0)

    LOADK(0);

    #pragma unroll 1
    for (int kk = 0; kk < D_IN / 64; ++kk) {
        #pragma unroll
        for (int i = 0; i < 4; ++i) {
            int m = i * 32 + sr;
            union { uint4 q; unsigned short h[8]; } pk;
            pk.h[0] = bf16b(a0[i].x); pk.h[1] = bf16b(a0[i].y);
            pk.h[2] = bf16b(a0[i].z); pk.h[3] = bf16b(a0[i].w);
            pk.h[4] = bf16b(a1[i].x); pk.h[5] = bf16b(a1[i].y);
            pk.h[6] = bf16b(a1[i].z); pk.h[7] = bf16b(a1[i].w);
            *(uint4*)((char*)As + ((m * 128 + skg * 16) ^ swz)) = pk.q;
            *(uint4*)((char*)Bs + ((m * 128 + skg * 16) ^ swz)) = wq[i];
        }
        if (kk < D_IN / 64 - 1) LOADK((kk + 1) * 64);
        __syncthreads();

        #pragma unroll
        for (int ks = 0; ks < 2; ++ks) {
            const int kb = (ks * 64 + lk * 16) ^ aswz;
            s8v af[4], bfr[4];
            #pragma unroll
            for (int f = 0; f < 4; ++f)
                af[f]  = *(const s8v*)((const char*)As + ((wm + f * 16 + lr) * 128 + kb));
            #pragma unroll
            for (int f = 0; f < 4; ++f)
                bfr[f] = *(const s8v*)((const char*)Bs + ((wn + f * 16 + lr) * 128 + kb));
            #pragma unroll
            for (int fm = 0; fm < 4; ++fm)
                #pragma unroll
                for (int fn = 0; fn < 4; ++fn)
                    acc[fm][fn] = __builtin_amdgcn_mfma_f32_16x16x32_bf16(
                        af[fm], bfr[fn], acc[fm][fn], 0, 0, 0);
        }
        __syncthreads();
    }
    #undef LOADK

    #pragma unroll
    for (int fm = 0; fm < 4; ++fm) {
        #pragma unroll
        for (int j = 0; j < 4; ++j) {
            int row = m0 + wm + fm * 16 + lk * 4 + j;
            if (row < N_NODES) {
                float s = dinv[row];
                #pragma unroll
                for (int fn = 0; fn < 4; ++fn) {
                    int col = n0 + wn + fn * 16 + lr;
                    yb[(size_t)row * D_OUT + col] = bf16b(acc[fm][fn][j] * s);
                }
            }
        }
    }
}

// ============ gather: out[c] = relu(dinv[c]*(yb[c] + sum yb[src]) + b) ============
__device__ __forceinline__ void add8(float* acc, uint4 q) {
    unsigned x;
    x = q.x; acc[0] += __uint_as_float(x << 16); acc[1] += __uint_as_float(x & 0xffff0000u);
    x = q.y; acc[2] += __uint_as_float(x << 16); acc[3] += __uint_as_float(x & 0xffff0000u);
    x = q.z; acc[4] += __uint_as_float(x << 16); acc[5] += __uint_as_float(x & 0xffff0000u);
    x = q.w; acc[6] += __uint_as_float(x << 16); acc[7] += __uint_as_float(x & 0xffff0000u);
}

__launch_bounds__(256)
__global__ void k_gather(const int* __restrict__ row_ptr, const int* __restrict__ csr_src,
                         const unsigned short* __restrict__ yb, const float* __restrict__ dinv,
                         const float* __restrict__ bias, float* __restrict__ out)
{
    const int c  = blockIdx.x * 4 + (threadIdx.x >> 6);
    const int l  = threadIdx.x & 63;
    const int eg = l >> 5;
    const int cs = l & 31;
    const size_t colb = (size_t)cs * 8;

    float acc[8] = {0.f,0.f,0.f,0.f,0.f,0.f,0.f,0.f};

    const int s = row_ptr[c];
    const int e = row_ptr[c + 1];

    int i = s + eg;
    while (i + 14 < e) {
        int r[8];
        #pragma unroll
        for (int u = 0; u < 8; ++u) r[u] = csr_src[i + 2 * u];
        uint4 v[8];
        #pragma unroll
        for (int u = 0; u < 8; ++u) v[u] = *(const uint4*)&yb[(size_t)r[u] * D_OUT + colb];
        #pragma unroll
        for (int u = 0; u < 8; ++u) add8(acc, v[u]);
        i += 16;
    }
    if (i + 6 < e) {
        int r[4];
        #pragma unroll
        for (int u = 0; u < 4; ++u) r[u] = csr_src[i + 2 * u];
        uint4 v[4];
        #pragma unroll
        for (int u = 0; u < 4; ++u) v[u] = *(const uint4*)&yb[(size_t)r[u] * D_OUT + colb];
        #pragma unroll
        for (int u = 0; u < 4; ++u) add8(acc, v[u]);
        i += 8;
    }
    while (i < e) {
        int r = csr_src[i];
        uint4 v = *(const uint4*)&yb[(size_t)r * D_OUT + colb];
        add8(acc, v);
        i += 2;
    }

    #pragma unroll
    for (int u = 0; u < 8; ++u) acc[u] += __shfl_xor(acc[u], 32, 64);

    uint4 sv = *(const uint4*)&yb[(size_t)c * D_OUT + colb];
    add8(acc, sv);

    if (eg == 0) {
        const float sc = dinv[c];
        float4 b0 = *(const float4*)&bias[colb];
        float4 b1 = *(const float4*)&bias[colb + 4];
        float4 o0, o1;
        o0.x = fmaxf(fmaf(acc[0], sc, b0.x), 0.f);
        o0.y = fmaxf(fmaf(acc[1], sc, b0.y), 0.f);
        o0.z = fmaxf(fmaf(acc[2], sc, b0.z), 0.f);
        o0.w = fmaxf(fmaf(acc[3], sc, b0.w), 0.f);
        o1.x = fmaxf(fmaf(acc[4], sc, b1.x), 0.f);
        o1.y = fmaxf(fmaf(acc[5], sc, b1.y), 0.f);
        o1.z = fmaxf(fmaf(acc[6], sc, b1.z), 0.f);
        o1.w = fmaxf(fmaf(acc[7], sc, b1.w), 0.f);
        float* dst = &out[(size_t)c * D_OUT + colb];
        *(float4*)dst       = o0;
        *(float4*)(dst + 4) = o1;
    }
}

extern "C" void kernel_launch(void* const* d_in, const int* in_sizes, int n_in,
                              void* d_out, int out_size, void* d_ws, size_t ws_size,
                              hipStream_t stream) {
    const float* x   = (const float*)d_in[0];
    const int*   ei  = (const int*)d_in[1];
    const float* W   = (const float*)d_in[2];
    const float* b   = (const float*)d_in[3];
    float*       out = (float*)d_out;

    const int* row = ei;
    const int* col = ei + N_EDGES;

    char* p = (char*)d_ws;
    unsigned short* yb = (unsigned short*)p;  p += (size_t)N_NODES * D_OUT * 2;   // 25.6 MB
    unsigned short* Wt = (unsigned short*)p;  p += (size_t)D_OUT * D_IN * 2;      // 256 KB
    int*   csr_src = (int*)p;                 p += (size_t)N_EDGES * 4;           // 3.2 MB
    int*   cnt     = (int*)p;                 p += (size_t)N_NODES * 4;
    int*   row_ptr = (int*)p;                 p += (size_t)(N_NODES + 4) * 4;
    int*   cursor  = (int*)p;                 p += (size_t)N_NODES * 4;
    float* dinv    = (float*)p;               p += (size_t)N_NODES * 4;
    int*   bsum    = (int*)p;                 p += (size_t)NBLK_SCAN * 4;
    int*   boff    = (int*)p;                 p += (size_t)NBLK_SCAN * 4;

    hipMemsetAsync(cnt, 0, (size_t)N_NODES * sizeof(int), stream);
    k_count<<<(N_EDGES + 255) / 256, 256, 0, stream>>>(col, cnt);
    k_scan1<<<NBLK_SCAN, 256, 0, stream>>>(cnt, bsum);
    k_scan2<<<1, 64, 0, stream>>>(bsum, boff);
    k_scan3<<<NBLK_SCAN, 256, 0, stream>>>(cnt, boff, row_ptr, dinv, cursor);
    k_fill <<<(N_EDGES + 255) / 256, 256, 0, stream>>>(row, col, cursor, csr_src);
    k_wt   <<<D_IN, D_OUT, 0, stream>>>(W, Wt);

    k_gemm<<<((N_NODES + 127) / 128) * 2, 256, 0, stream>>>(x, Wt, dinv, yb);

    k_gather<<<N_NODES / 4, 256, 0, stream>>>(row_ptr, csr_src, yb, dinv, b, out);
}

// Round 7
// 213.590 us; speedup vs baseline: 1.1569x; 1.1569x over previous
//
#include <hip/hip_runtime.h>
#include <hip/hip_bf16.h>

#define N_NODES 50000
#define N_EDGES 800000
#define D_IN    512
#define D_OUT   256
#define NBLK_SCAN ((N_NODES + 1023) / 1024)   // 49
#define GEMM_NWG (((N_NODES + 127) / 128) * 2)  // 782
#define GEMM_Q   (GEMM_NWG / 8)                  // 97
#define GEMM_R   (GEMM_NWG % 8)                  // 6

typedef short s8v  __attribute__((ext_vector_type(8)));
typedef float f32x4 __attribute__((ext_vector_type(4)));

__device__ __forceinline__ unsigned short bf16b(float f) {
    __hip_bfloat16 h = __float2bfloat16(f);
    return *reinterpret_cast<unsigned short*>(&h);
}

// global -> LDS direct copy, 16B per lane; LDS dest is wave-uniform base + lane*16
#define GLD16(gp, lp)                                                           \
    __builtin_amdgcn_global_load_lds(                                           \
        (const __attribute__((address_space(1))) unsigned int*)(const void*)(gp),\
        (__attribute__((address_space(3))) unsigned int*)(void*)(lp), 16, 0, 0)

__device__ __forceinline__ int wave_incl_scan(int v, int lane) {
    #pragma unroll
    for (int d = 1; d < 64; d <<= 1) {
        int u = __shfl_up(v, d, 64);
        if (lane >= d) v += u;
    }
    return v;
}

// ============ CSR build ============

__global__ void k_count(const int* __restrict__ col, int* __restrict__ cnt) {
    int i = blockIdx.x * 256 + threadIdx.x;
    if (i < N_EDGES) atomicAdd(&cnt[col[i]], 1);
}

__launch_bounds__(256)
__global__ void k_scan1(const int* __restrict__ cnt, int* __restrict__ bsum) {
    const int t = threadIdx.x, b = blockIdx.x;
    const int idx = b * 1024 + t * 4;
    int4 v = make_int4(0, 0, 0, 0);
    if (idx < N_NODES) v = *(const int4*)&cnt[idx];
    int s = v.x + v.y + v.z + v.w;
    #pragma unroll
    for (int d = 1; d < 64; d <<= 1) s += __shfl_xor(s, d, 64);
    __shared__ int ws[4];
    if ((t & 63) == 0) ws[t >> 6] = s;
    __syncthreads();
    if (t == 0) bsum[b] = ws[0] + ws[1] + ws[2] + ws[3];
}

__global__ void k_scan2(const int* __restrict__ bsum, int* __restrict__ boff) {
    const int t = threadIdx.x;   // 64
    int v = (t < NBLK_SCAN) ? bsum[t] : 0;
    int inc = wave_incl_scan(v, t);
    if (t < NBLK_SCAN) boff[t] = inc - v;
}

__launch_bounds__(256)
__global__ void k_scan3(const int* __restrict__ cnt, const int* __restrict__ boff,
                        int* __restrict__ row_ptr, float* __restrict__ dinv,
                        int* __restrict__ cursor) {
    const int t = threadIdx.x, b = blockIdx.x;
    const int lane = t & 63, wv = t >> 6;
    const int idx = b * 1024 + t * 4;
    int4 v = make_int4(0, 0, 0, 0);
    if (idx < N_NODES) v = *(const int4*)&cnt[idx];
    int s = v.x + v.y + v.z + v.w;
    int isc = wave_incl_scan(s, lane);
    __shared__ int wsum[4];
    if (lane == 63) wsum[wv] = isc;
    __syncthreads();
    int off = boff[b];
    #pragma unroll
    for (int i = 0; i < 4; ++i)
        if (i < wv) off += wsum[i];
    int p0 = off + isc - s;
    int p1 = p0 + v.x;
    int p2 = p1 + v.y;
    int p3 = p2 + v.z;
    if (idx < N_NODES) {
        row_ptr[idx + 0] = p0; cursor[idx + 0] = p0; dinv[idx + 0] = rsqrtf(1.f + (float)v.x);
        row_ptr[idx + 1] = p1; cursor[idx + 1] = p1; dinv[idx + 1] = rsqrtf(1.f + (float)v.y);
        row_ptr[idx + 2] = p2; cursor[idx + 2] = p2; dinv[idx + 2] = rsqrtf(1.f + (float)v.z);
        row_ptr[idx + 3] = p3; cursor[idx + 3] = p3; dinv[idx + 3] = rsqrtf(1.f + (float)v.w);
    }
    if (b == 0 && t == 0) row_ptr[N_NODES] = N_EDGES;
}

__global__ void k_fill(const int* __restrict__ row, const int* __restrict__ col,
                       int* __restrict__ cursor, int* __restrict__ csr_src) {
    int i = blockIdx.x * 256 + threadIdx.x;
    if (i < N_EDGES) {
        int pos = atomicAdd(&cursor[col[i]], 1);
        csr_src[pos] = row[i];
    }
}

// ============ W transpose + bf16 convert ============
__global__ void k_wt(const float* __restrict__ W, unsigned short* __restrict__ Wt) {
    int k = blockIdx.x;      // 512
    int n = threadIdx.x;     // 256
    Wt[(size_t)n * D_IN + k] = bf16b(W[(size_t)k * D_OUT + n]);
}

// ============ x convert: xb[r][k] = bf16(x[r][k] * dinv[r]) ============
// dinv folds here (GEMM is linear in rows) -> GEMM epilogue needs no dinv.
__launch_bounds__(256)
__global__ void k_xb(const float* __restrict__ x, const float* __restrict__ dinv,
                     unsigned short* __restrict__ xb) {
    int idx = blockIdx.x * 256 + threadIdx.x;      // one 8-elem group per thread
    const int tot = N_NODES * D_IN / 8;            // 3,200,000
    if (idx >= tot) return;
    int node = idx >> 6;                           // 64 groups per row
    float s = dinv[node];
    const float4* src = (const float4*)x + (size_t)idx * 2;
    float4 v0 = src[0], v1 = src[1];
    union { uint4 q; unsigned short h[8]; } pk;
    pk.h[0] = bf16b(v0.x * s); pk.h[1] = bf16b(v0.y * s);
    pk.h[2] = bf16b(v0.z * s); pk.h[3] = bf16b(v0.w * s);
    pk.h[4] = bf16b(v1.x * s); pk.h[5] = bf16b(v1.y * s);
    pk.h[6] = bf16b(v1.z * s); pk.h[7] = bf16b(v1.w * s);
    ((uint4*)xb)[idx] = pk.q;
}

// ============ MFMA GEMM: yb = xb @ Wt^T (both bf16, global_load_lds staged) ============
// 128x128 tile, BK=64, 4 waves. LDS dest linear; source address pre-swizzled
// (lane l loads chunk (l&7)^(l>>3)) so ds_read-side XOR swizzle stays conflict-free.
__launch_bounds__(256)
__global__ void k_gemm(const unsigned short* __restrict__ xb,  // [N_NODES,512] bf16 (dinv-scaled)
                       const unsigned short* __restrict__ Wt,  // [256,512] bf16
                       unsigned short* __restrict__ yb)        // [N_NODES,256] bf16
{
    __shared__ __align__(16) unsigned short As[128 * 64];   // 16 KB
    __shared__ __align__(16) unsigned short Bs[128 * 64];   // 16 KB

    // bijective XCD swizzle (m204): blocks sharing an A-panel land on one XCD
    int orig = blockIdx.x;
    int xcd = orig % 8, pos = orig / 8;
    int wg = (xcd < GEMM_R) ? xcd * (GEMM_Q + 1) + pos
                            : GEMM_R * (GEMM_Q + 1) + (xcd - GEMM_R) * GEMM_Q + pos;
    const int nt = wg & 1;
    const int mt = wg >> 1;
    const int m0 = mt * 128;
    const int n0 = nt * 128;

    const int t  = threadIdx.x;
    const int w  = t >> 6;
    const int l  = t & 63;
    const int wm = (w >> 1) * 64;
    const int wn = (w & 1) * 64;
    const int lr = l & 15;
    const int lk = l >> 4;
    const int aswz = (lr & 7) << 4;

    // staging source offsets: group g covers LDS rows g*8..g*8+7; lane l ->
    // row g*8 + (l>>3), chunk (l&7); source chunk j = (l&7)^(l>>3)
    const int srow = l >> 3;
    const int srcj = (l & 7) ^ srow;

    size_t aoff[4];
    size_t boff[4];
    #pragma unroll
    for (int i = 0; i < 4; ++i) {
        int g = w * 4 + i;
        int am = m0 + g * 8 + srow;
        if (am >= N_NODES) am = 0;                 // tail clamp; outputs guarded
        aoff[i] = (size_t)am * D_IN + srcj * 8;
        int bn = n0 + g * 8 + srow;
        boff[i] = (size_t)bn * D_IN + srcj * 8;
    }

    f32x4 acc[4][4] = {};

    for (int kk = 0; kk < D_IN; kk += 64) {
        #pragma unroll
        for (int i = 0; i < 4; ++i) {
            int g = w * 4 + i;
            GLD16(&xb[aoff[i] + kk], (char*)As + g * 1024);
            GLD16(&Wt[boff[i] + kk], (char*)Bs + g * 1024);
        }
        __syncthreads();

        #pragma unroll
        for (int ks = 0; ks < 2; ++ks) {
            const int kb = (ks * 64 + lk * 16) ^ aswz;
            s8v af[4], bfr[4];
            #pragma unroll
            for (int f = 0; f < 4; ++f)
                af[f]  = *(const s8v*)((const char*)As + ((wm + f * 16 + lr) * 128 + kb));
            #pragma unroll
            for (int f = 0; f < 4; ++f)
                bfr[f] = *(const s8v*)((const char*)Bs + ((wn + f * 16 + lr) * 128 + kb));
            #pragma unroll
            for (int fm = 0; fm < 4; ++fm)
                #pragma unroll
                for (int fn = 0; fn < 4; ++fn)
                    acc[fm][fn] = __builtin_amdgcn_mfma_f32_16x16x32_bf16(
                        af[fm], bfr[fn], acc[fm][fn], 0, 0, 0);
        }
        __syncthreads();
    }

    #pragma unroll
    for (int fm = 0; fm < 4; ++fm) {
        #pragma unroll
        for (int j = 0; j < 4; ++j) {
            int row = m0 + wm + fm * 16 + lk * 4 + j;
            if (row < N_NODES) {
                #pragma unroll
                for (int fn = 0; fn < 4; ++fn) {
                    int col = n0 + wn + fn * 16 + lr;
                    yb[(size_t)row * D_OUT + col] = bf16b(acc[fm][fn][j]);
                }
            }
        }
    }
}

// ============ gather: out[c] = relu(dinv[c]*(yb[c] + sum yb[src]) + b) ============
__device__ __forceinline__ void add8(float* acc, uint4 q) {
    unsigned x;
    x = q.x; acc[0] += __uint_as_float(x << 16); acc[1] += __uint_as_float(x & 0xffff0000u);
    x = q.y; acc[2] += __uint_as_float(x << 16); acc[3] += __uint_as_float(x & 0xffff0000u);
    x = q.z; acc[4] += __uint_as_float(x << 16); acc[5] += __uint_as_float(x & 0xffff0000u);
    x = q.w; acc[6] += __uint_as_float(x << 16); acc[7] += __uint_as_float(x & 0xffff0000u);
}

__launch_bounds__(256)
__global__ void k_gather(const int* __restrict__ row_ptr, const int* __restrict__ csr_src,
                         const unsigned short* __restrict__ yb, const float* __restrict__ dinv,
                         const float* __restrict__ bias, float* __restrict__ out)
{
    const int c  = blockIdx.x * 4 + (threadIdx.x >> 6);
    const int l  = threadIdx.x & 63;
    const int eg = l >> 5;
    const int cs = l & 31;
    const size_t colb = (size_t)cs * 8;

    float acc[8] = {0.f,0.f,0.f,0.f,0.f,0.f,0.f,0.f};

    const int s = row_ptr[c];
    const int e = row_ptr[c + 1];

    int i = s + eg;
    while (i + 14 < e) {
        int r[8];
        #pragma unroll
        for (int u = 0; u < 8; ++u) r[u] = csr_src[i + 2 * u];
        uint4 v[8];
        #pragma unroll
        for (int u = 0; u < 8; ++u) v[u] = *(const uint4*)&yb[(size_t)r[u] * D_OUT + colb];
        #pragma unroll
        for (int u = 0; u < 8; ++u) add8(acc, v[u]);
        i += 16;
    }
    if (i + 6 < e) {
        int r[4];
        #pragma unroll
        for (int u = 0; u < 4; ++u) r[u] = csr_src[i + 2 * u];
        uint4 v[4];
        #pragma unroll
        for (int u = 0; u < 4; ++u) v[u] = *(const uint4*)&yb[(size_t)r[u] * D_OUT + colb];
        #pragma unroll
        for (int u = 0; u < 4; ++u) add8(acc, v[u]);
        i += 8;
    }
    while (i < e) {
        int r = csr_src[i];
        uint4 v = *(const uint4*)&yb[(size_t)r * D_OUT + colb];
        add8(acc, v);
        i += 2;
    }

    #pragma unroll
    for (int u = 0; u < 8; ++u) acc[u] += __shfl_xor(acc[u], 32, 64);

    uint4 sv = *(const uint4*)&yb[(size_t)c * D_OUT + colb];
    add8(acc, sv);

    if (eg == 0) {
        const float sc = dinv[c];
        float4 b0 = *(const float4*)&bias[colb];
        float4 b1 = *(const float4*)&bias[colb + 4];
        float4 o0, o1;
        o0.x = fmaxf(fmaf(acc[0], sc, b0.x), 0.f);
        o0.y = fmaxf(fmaf(acc[1], sc, b0.y), 0.f);
        o0.z = fmaxf(fmaf(acc[2], sc, b0.z), 0.f);
        o0.w = fmaxf(fmaf(acc[3], sc, b0.w), 0.f);
        o1.x = fmaxf(fmaf(acc[4], sc, b1.x), 0.f);
        o1.y = fmaxf(fmaf(acc[5], sc, b1.y), 0.f);
        o1.z = fmaxf(fmaf(acc[6], sc, b1.z), 0.f);
        o1.w = fmaxf(fmaf(acc[7], sc, b1.w), 0.f);
        float* dst = &out[(size_t)c * D_OUT + colb];
        *(float4*)dst       = o0;
        *(float4*)(dst + 4) = o1;
    }
}

extern "C" void kernel_launch(void* const* d_in, const int* in_sizes, int n_in,
                              void* d_out, int out_size, void* d_ws, size_t ws_size,
                              hipStream_t stream) {
    const float* x   = (const float*)d_in[0];
    const int*   ei  = (const int*)d_in[1];
    const float* W   = (const float*)d_in[2];
    const float* b   = (const float*)d_in[3];
    float*       out = (float*)d_out;

    const int* row = ei;
    const int* col = ei + N_EDGES;

    char* p = (char*)d_ws;
    unsigned short* yb = (unsigned short*)p;  p += (size_t)N_NODES * D_OUT * 2;   // 25.6 MB
    unsigned short* xb = (unsigned short*)p;  p += (size_t)N_NODES * D_IN * 2;    // 51.2 MB
    unsigned short* Wt = (unsigned short*)p;  p += (size_t)D_OUT * D_IN * 2;      // 256 KB
    int*   csr_src = (int*)p;                 p += (size_t)N_EDGES * 4;           // 3.2 MB
    int*   cnt     = (int*)p;                 p += (size_t)N_NODES * 4;
    int*   row_ptr = (int*)p;                 p += (size_t)(N_NODES + 4) * 4;
    int*   cursor  = (int*)p;                 p += (size_t)N_NODES * 4;
    float* dinv    = (float*)p;               p += (size_t)N_NODES * 4;
    int*   bsum    = (int*)p;                 p += (size_t)NBLK_SCAN * 4;
    int*   boff    = (int*)p;                 p += (size_t)NBLK_SCAN * 4;

    hipMemsetAsync(cnt, 0, (size_t)N_NODES * sizeof(int), stream);
    k_count<<<(N_EDGES + 255) / 256, 256, 0, stream>>>(col, cnt);
    k_scan1<<<NBLK_SCAN, 256, 0, stream>>>(cnt, bsum);
    k_scan2<<<1, 64, 0, stream>>>(bsum, boff);
    k_scan3<<<NBLK_SCAN, 256, 0, stream>>>(cnt, boff, row_ptr, dinv, cursor);
    k_fill <<<(N_EDGES + 255) / 256, 256, 0, stream>>>(row, col, cursor, csr_src);
    k_wt   <<<D_IN, D_OUT, 0, stream>>>(W, Wt);
    k_xb   <<<(N_NODES * D_IN / 8 + 255) / 256, 256, 0, stream>>>(x, dinv, xb);

    k_gemm<<<GEMM_NWG, 256, 0, stream>>>(xb, Wt, yb);

    k_gather<<<N_NODES / 4, 256, 0, stream>>>(row_ptr, csr_src, yb, dinv, b, out);
}